// Round 11
// baseline (1172.380 us; speedup 1.0000x reference)
//
#include <hip/hip_runtime.h>
#include <stdint.h>

// ---------------------------------------------------------------------------
// LSTM  T=512, B=64, I=H=512.
// r11 = r9-proven rec body (948us) + GEMM FUSED AS CONCURRENT PRODUCER WGS:
//       grid 256 = 128 GEMM wgs (bids 0-127, dispatched first => deadlock-
//       free) + 128 rec wgs (bids 128-255). GEMM sweeps tiles in t-order and
//       publishes per-bm completion counters (release); rec gates step t on
//       cnt[(4t+gb)>>3]==16 (speculative check, verified after channel poll).
//       xg reads are sc0 sc1 (MALL-direct, latency hidden under the poll) =>
//       no stale-cache hazards. All waits budget-bounded (fail-fast).
//  lstm_prep : r10 LDS-transposed prep + cnt zeroing.
// ---------------------------------------------------------------------------

typedef __attribute__((ext_vector_type(8))) short    short8;   // 8 x bf16
typedef __attribute__((ext_vector_type(4))) float    f32x4;
typedef __attribute__((ext_vector_type(4))) unsigned u32x4;
typedef __attribute__((ext_vector_type(2))) unsigned u32x2;

// ws layout (bytes)
#define XG_OFF    0ull                  // 134,217,728  (32768x2048 bf16, micro-tiled)
#define WBT_OFF   134217728ull          //   2,097,152  (2048 cols x 512 k bf16)
#define BIAS_OFF  136314880ull          //       8,192  (2048 f32)
#define HW_OFF    136323072ull          //     262,144  (2 par x 4 gb x 4 ws x 16 row x 64 u64)
#define CNT_OFF   136585216ull          //       1,024  (256 u32 per-bm counters)

static __device__ __forceinline__ unsigned short f2bf(float f) {
  unsigned u = __float_as_uint(f);
  unsigned r = (u + 0x7FFFu + ((u >> 16) & 1u)) >> 16;   // RNE to bf16
  return (unsigned short)r;
}
static __device__ __forceinline__ float bf2f(unsigned short u) {
  return __uint_as_float(((unsigned)u) << 16);
}
static __device__ __forceinline__ float sigmoidf_(float x) {
  return 1.0f / (1.0f + __expf(-x));
}
static __device__ __forceinline__ float tanhf_(float x) {
  return 1.0f - 2.0f / (__expf(2.0f * x) + 1.0f);
}

// ---------------------------------------------------------------------------
// prep: 1024 wgs. Tile-transpose Wx via LDS (both sides coalesced) + side
// jobs: bias (wg 0-7), h0 channel pack (wg 64-127), parity-1 invalidate
// (wg 128-191), cnt zero (wg 192).
__global__ __launch_bounds__(256) void lstm_prep(
    const float* __restrict__ W_ii, const float* __restrict__ W_if,
    const float* __restrict__ W_ig, const float* __restrict__ W_io,
    const float* __restrict__ b_ii, const float* __restrict__ b_if,
    const float* __restrict__ b_ig, const float* __restrict__ b_io,
    const float* __restrict__ b_hi, const float* __restrict__ b_hf,
    const float* __restrict__ b_hg, const float* __restrict__ b_ho,
    const float* __restrict__ h0, unsigned char* ws)
{
  unsigned short*     WbT  = (unsigned short*)(ws + WBT_OFF);
  float*              bias = (float*)(ws + BIAS_OFF);
  unsigned long long* hw64 = (unsigned long long*)(ws + HW_OFF);
  unsigned*           cnt  = (unsigned*)(ws + CNT_OFF);

  const int bid = (int)blockIdx.x, tid = threadIdx.x;

  __shared__ float lds[32][33];

  const int g  = bid >> 8;                   // 0..3
  const int tr = (bid >> 4) & 15;            // k-tile
  const int tc = bid & 15;                   // c-tile
  const float* W = (g == 0) ? W_ii : (g == 1) ? W_if : (g == 2) ? W_ig : W_io;

  {
    const int kl = tid >> 3;                 // 0..31 row in tile (k)
    const int c4 = (tid & 7) * 4;            // 0..28 col in tile (c)
    const float4 v = *reinterpret_cast<const float4*>(
        &W[(size_t)(tr * 32 + kl) * 512 + tc * 32 + c4]);
    lds[c4 + 0][kl] = v.x;
    lds[c4 + 1][kl] = v.y;
    lds[c4 + 2][kl] = v.z;
    lds[c4 + 3][kl] = v.w;
  }
  __syncthreads();
  {
    const int cl = tid >> 3;                 // 0..31 col (row of WbT)
    const int k4 = (tid & 7) * 4;            // 0..28 k
    const int gcol = g * 512 + tc * 32 + cl;
    uint2 p;
    p.x = (unsigned)f2bf(lds[cl][k4 + 0]) | ((unsigned)f2bf(lds[cl][k4 + 1]) << 16);
    p.y = (unsigned)f2bf(lds[cl][k4 + 2]) | ((unsigned)f2bf(lds[cl][k4 + 3]) << 16);
    *reinterpret_cast<uint2*>(&WbT[(size_t)gcol * 512 + tr * 32 + k4]) = p;
  }

  if (bid < 8) {                             // bias
    int i = bid * 256 + tid;
    int gg = i >> 9, c = i & 511;
    const float* bi = (gg == 0) ? b_ii : (gg == 1) ? b_if : (gg == 2) ? b_ig : b_io;
    const float* bh = (gg == 0) ? b_hi : (gg == 1) ? b_hf : (gg == 2) ? b_hg : b_ho;
    bias[i] = bi[c] + bh[c];
  } else if (bid >= 64 && bid < 128) {       // h0 pack, parity 0, tag 0
    int i = (bid - 64) * 256 + tid;          // 0..16383
    int r = i >> 8, wc = i & 255;
    int gb = r >> 4, row = r & 15, wsl = wc >> 6, c = wc & 63;
    unsigned lo = f2bf(h0[(size_t)r * 512 + wc * 2]);
    unsigned hi = f2bf(h0[(size_t)r * 512 + wc * 2 + 1]);
    hw64[((size_t)(gb * 4 + wsl) * 16 + row) * 64 + c] =
        (unsigned long long)(lo | (hi << 16));
  } else if (bid >= 128 && bid < 192) {      // parity 1: invalid tags
    int i = (bid - 128) * 256 + tid;
    hw64[16384 + i] = 0xFFFFFFFF00000000ull;
  } else if (bid == 192) {                   // xg progress counters
    cnt[tid] = 0u;
  }
}

// ---------------------------------------------------------------------------
// Fused kernel. bids 0-127: GEMM producer role (xg = x@Wx + b, t-ordered
// sweeps + cnt release). bids 128-255: r9-proven recurrence role.
__global__ __launch_bounds__(256, 1) void lstm_fused(
    const float* __restrict__ x,
    const float* __restrict__ Whi, const float* __restrict__ Whf,
    const float* __restrict__ Whg, const float* __restrict__ Who,
    const float* __restrict__ c0, unsigned char* ws, float* __restrict__ out)
{
  const int bid = (int)blockIdx.x;
  const int tid = threadIdx.x, lane = tid & 63, w = tid >> 6;

  unsigned long long* hw64 = (unsigned long long*)(ws + HW_OFF);
  unsigned*           cnt  = (unsigned*)(ws + CNT_OFF);

  // LDS (union of both roles; 80 KiB total, 1 wg/CU either way)
  __shared__ unsigned hdat[4][1024];         // rec: per-wave data u32, swizzled
  __shared__ float glds[2][4][4][16][16];    // rec: [par][wave][gate][row][col]
  __shared__ unsigned short As[128 * 64];    // gemm: [row][k] bf16
  __shared__ unsigned short Bs[128 * 64];    // gemm: [col][k] bf16

  if (bid < 128) {
    // =================== GEMM producer role ===================
    const unsigned short* WbT  = (const unsigned short*)(ws + WBT_OFF);
    const float*          bias = (const float*)(ws + BIAS_OFF);
    unsigned short*       xg   = (unsigned short*)(ws + XG_OFF);
    const int j  = bid;
    const int wr = w >> 1, wc = w & 1;

    for (int s = 0; s < 32; ++s) {
      const int bm = 8 * s + (j >> 4);       // t-ordered: sweep s covers bm 8s..8s+7
      const int bn = j & 15;
      const int row0 = bm * 128, col0 = bn * 128;

      f32x4 acc[4][4] = {};
      for (int k0 = 0; k0 < 512; k0 += 64) {
        __syncthreads();
#pragma unroll
        for (int u = 0; u < 8; ++u) {
          int idx = u * 256 + tid;
          int r = idx >> 4, quad = idx & 15;
          const float4 v = *reinterpret_cast<const float4*>(
              &x[(size_t)(row0 + r) * 512 + k0 + quad * 4]);
          uint2 p;
          p.x = (unsigned)f2bf(v.x) | ((unsigned)f2bf(v.y) << 16);
          p.y = (unsigned)f2bf(v.z) | ((unsigned)f2bf(v.w) << 16);
          *reinterpret_cast<uint2*>(&As[r * 64 + quad * 4]) = p;
        }
#pragma unroll
        for (int u = 0; u < 4; ++u) {
          int idx = u * 256 + tid;
          int cl = idx >> 3, ch = idx & 7;
          *reinterpret_cast<uint4*>(&Bs[cl * 64 + ch * 8]) =
              *reinterpret_cast<const uint4*>(&WbT[(size_t)(col0 + cl) * 512 + k0 + ch * 8]);
        }
        __syncthreads();
#pragma unroll
        for (int kk = 0; kk < 64; kk += 32) {
          short8 a[4], b[4];
#pragma unroll
          for (int m = 0; m < 4; ++m)
            a[m] = *reinterpret_cast<const short8*>(
                &As[(wr * 64 + m * 16 + (lane & 15)) * 64 + kk + (lane >> 4) * 8]);
#pragma unroll
          for (int n = 0; n < 4; ++n)
            b[n] = *reinterpret_cast<const short8*>(
                &Bs[(wc * 64 + n * 16 + (lane & 15)) * 64 + kk + (lane >> 4) * 8]);
#pragma unroll
          for (int m = 0; m < 4; ++m)
#pragma unroll
            for (int n = 0; n < 4; ++n)
              acc[m][n] = __builtin_amdgcn_mfma_f32_16x16x32_bf16(a[m], b[n], acc[m][n], 0, 0, 0);
        }
      }
      // epilogue: +bias -> bf16 micro-tiled; sc0 sc1 (MALL write-through)
#pragma unroll
      for (int m = 0; m < 4; ++m) {
        int rowtile = bm * 8 + wr * 4 + m;
#pragma unroll
        for (int n = 0; n < 4; ++n) {
          int coltile = bn * 8 + wc * 4 + n;
          float bv = bias[coltile * 16 + (lane & 15)];
          u32x2 p;
          p[0] = (unsigned)f2bf(acc[m][n][0] + bv) | ((unsigned)f2bf(acc[m][n][1] + bv) << 16);
          p[1] = (unsigned)f2bf(acc[m][n][2] + bv) | ((unsigned)f2bf(acc[m][n][3] + bv) << 16);
          unsigned short* dst = &xg[((size_t)rowtile * 128 + coltile) * 256 + lane * 4];
          asm volatile("global_store_dwordx2 %0, %1, off sc0 sc1"
                       :: "v"(dst), "v"(p) : "memory");
        }
      }
      asm volatile("s_waitcnt vmcnt(0)" ::: "memory");
      __syncthreads();                       // all waves' stores drained
      if (tid == 0)
        __hip_atomic_fetch_add(&cnt[bm], 1u, __ATOMIC_RELEASE,
                               __HIP_MEMORY_SCOPE_AGENT);
    }
    return;
  }

  // =================== recurrence role (r9 body) ===================
  const int rbid = bid - 128;
  const int gb = rbid & 3;                   // batch group (16 rows)
  const int gc = rbid >> 2;                  // col group (16 h-cols)

  const unsigned short* xg = (const unsigned short*)(ws + XG_OFF);

  // ---- load Wh fragments (split bf16 hi+lo), K-slice of this wave ----
  short8 bhi[4][4], blo[4][4];               // [gate][kkl]
  {
    const int colg = gc * 16 + (lane & 15);
    const int krow = (lane >> 4) * 8;
#pragma unroll
    for (int g = 0; g < 4; ++g) {
      const float* P = (g == 0) ? Whi : (g == 1) ? Whf : (g == 2) ? Whg : Who;
#pragma unroll
      for (int kkl = 0; kkl < 4; ++kkl) {
        short8 h8, l8;
#pragma unroll
        for (int i = 0; i < 8; ++i) {
          int k = w * 128 + kkl * 32 + krow + i;
          float wv = P[(size_t)k * 512 + colg];
          unsigned short hb = f2bf(wv);
          h8[i] = (short)hb;
          l8[i] = (short)f2bf(wv - bf2f(hb));
        }
        bhi[g][kkl] = h8; blo[g][kkl] = l8;
      }
    }
  }

  const int crow = tid >> 4, ccol = tid & 15;       // this thread's (row,col)
  float c = c0[(size_t)(gb * 16 + crow) * 512 + gc * 16 + ccol];

  float* hT = out + 16777216;
  float* cT = out + 16777216 + 32768;
  const int e_ix = (crow >> 2) * 64 + ccol * 4 + (crow & 3);   // micro-tile elem
  int bleft = 30000000;                      // global poll budget (anti-hang)

  for (int t = 0; t < 512; ++t) {
    const int par = t & 1;
    const unsigned tagw = (unsigned)t;
    const int bmn = (t * 4 + gb) >> 3;       // xg tile-row needed this step

    // speculative xg-ready check + MALL-direct xg loads (hidden under poll)
    unsigned cntv = __hip_atomic_load(&cnt[bmn], __ATOMIC_RELAXED,
                                      __HIP_MEMORY_SCOPE_AGENT);
    const size_t xb = (size_t)(t * 4 + gb) * 128 * 256;
    const unsigned short* xp0 = &xg[xb + (size_t)(0 * 32 + gc) * 256 + e_ix];
    const unsigned short* xp1 = &xg[xb + (size_t)(1 * 32 + gc) * 256 + e_ix];
    const unsigned short* xp2 = &xg[xb + (size_t)(2 * 32 + gc) * 256 + e_ix];
    const unsigned short* xp3 = &xg[xb + (size_t)(3 * 32 + gc) * 256 + e_ix];
    unsigned xu0, xu1, xu2, xu3;
    asm volatile("global_load_ushort %0, %1, off sc0 sc1" : "=v"(xu0) : "v"(xp0));
    asm volatile("global_load_ushort %0, %1, off sc0 sc1" : "=v"(xu1) : "v"(xp1));
    asm volatile("global_load_ushort %0, %1, off sc0 sc1" : "=v"(xu2) : "v"(xp2));
    asm volatile("global_load_ushort %0, %1, off sc0 sc1" : "=v"(xu3) : "v"(xp3));

    const unsigned long long* blk =
        hw64 + (size_t)((par * 4 + gb) * 4 + w) * 1024;

    // ---- fused bulk-poll: the coalesced read IS the poll (r9) ----
    u32x4 dv[8];
    const char* lbase = (const char*)blk + lane * 16;
    for (;;) {
#pragma unroll
      for (int i = 0; i < 8; ++i)
        asm volatile("global_load_dwordx4 %0, %1, off sc0 sc1"
                     : "=v"(dv[i]) : "v"(lbase + (size_t)i * 1024));
      asm volatile("s_waitcnt vmcnt(0)"
                   : "+v"(dv[0]), "+v"(dv[1]), "+v"(dv[2]), "+v"(dv[3]),
                     "+v"(dv[4]), "+v"(dv[5]), "+v"(dv[6]), "+v"(dv[7])
                   :: "memory");
      bool ok = true;
#pragma unroll
      for (int i = 0; i < 8; ++i)
        ok = ok && (dv[i][1] == tagw) && (dv[i][3] == tagw);
      if (__all(ok) || --bleft <= 0) break;
      __builtin_amdgcn_s_sleep(1);           // backoff: cap poll congestion
    }

    // ---- xg-ready verification (slow path only in the first steps) ----
    if (cntv < 16u) {
      do {
        cntv = __hip_atomic_load(&cnt[bmn], __ATOMIC_RELAXED,
                                 __HIP_MEMORY_SCOPE_AGENT);
      } while (cntv < 16u && --bleft > 0);
      asm volatile("global_load_ushort %0, %1, off sc0 sc1" : "=v"(xu0) : "v"(xp0));
      asm volatile("global_load_ushort %0, %1, off sc0 sc1" : "=v"(xu1) : "v"(xp1));
      asm volatile("global_load_ushort %0, %1, off sc0 sc1" : "=v"(xu2) : "v"(xp2));
      asm volatile("global_load_ushort %0, %1, off sc0 sc1" : "=v"(xu3) : "v"(xp3));
      asm volatile("s_waitcnt vmcnt(0)"
                   : "+v"(xu0), "+v"(xu1), "+v"(xu2), "+v"(xu3) :: "memory");
    }
    float xgi = bf2f((unsigned short)xu0);
    float xgf = bf2f((unsigned short)xu1);
    float xgg = bf2f((unsigned short)xu2);
    float xgo = bf2f((unsigned short)xu3);

    // ---- redistribute data u32s via swizzled LDS (conflict-free-ish)
#pragma unroll
    for (int i = 0; i < 8; ++i) {
      int k = i * 128 + lane * 2;
      int row = k >> 6;
      int sw = k ^ ((row & 7) << 2);
      u32x2 p2; p2[0] = dv[i][0]; p2[1] = dv[i][2];
      *reinterpret_cast<u32x2*>(&hdat[w][sw]) = p2;
    }
    asm volatile("s_waitcnt lgkmcnt(0)" ::: "memory");
    __builtin_amdgcn_sched_barrier(0);

    // ---- MFMA partials over this wave's K-slice
    f32x4 acc[4] = {};
#pragma unroll
    for (int kkl = 0; kkl < 4; ++kkl) {
      int base = (lane & 15) * 64 + kkl * 16 + (lane >> 4) * 4;
      int sw = base ^ ((lane & 7) << 2);
      union { u32x4 v; short8 s; } fr;
      fr.v = *reinterpret_cast<const u32x4*>(&hdat[w][sw]);
#pragma unroll
      for (int g = 0; g < 4; ++g) {
        acc[g] = __builtin_amdgcn_mfma_f32_16x16x32_bf16(fr.s, bhi[g][kkl], acc[g], 0, 0, 0);
        acc[g] = __builtin_amdgcn_mfma_f32_16x16x32_bf16(fr.s, blo[g][kkl], acc[g], 0, 0, 0);
      }
    }
    // ---- exchange K-partials via LDS (parity buffer, single barrier)
#pragma unroll
    for (int g = 0; g < 4; ++g)
#pragma unroll
      for (int j = 0; j < 4; ++j)
        glds[par][w][g][(lane >> 4) * 4 + j][lane & 15] = acc[g][j];
    __syncthreads();

    float gi = xgi, gf = xgf, gg = xgg, go = xgo;
#pragma unroll
    for (int ww = 0; ww < 4; ++ww) {
      gi += glds[par][ww][0][crow][ccol];
      gf += glds[par][ww][1][crow][ccol];
      gg += glds[par][ww][2][crow][ccol];
      go += glds[par][ww][3][crow][ccol];
    }
    float iv = sigmoidf_(gi), fv = sigmoidf_(gf), gv = tanhf_(gg), ov = sigmoidf_(go);
    c = fv * c + iv * gv;
    float h = ov * c;                       // NOTE: no tanh(c), per reference

    // ---- publish h_{t+1} (tag rides in the same 8B word; coalesced lines)
    if (t != 511) {
      float hp = __shfl_xor(h, 1);
      if ((ccol & 1) == 0) {
        unsigned data = (unsigned)f2bf(h) | ((unsigned)f2bf(hp) << 16);
        u32x2 wp; wp[0] = data; wp[1] = (unsigned)(t + 1);
        unsigned long long* dst =
            hw64 + ((size_t)((((t + 1) & 1) * 4 + gb) * 4 + (gc >> 3)) * 16 + crow) * 64 +
            (gc & 7) * 8 + (ccol >> 1);
        asm volatile("global_store_dwordx2 %0, %1, off sc0 sc1"
                     :: "v"(dst), "v"(wp) : "memory");
      }
    }

    out[(size_t)t * 32768 + (size_t)(gb * 16 + crow) * 512 + gc * 16 + ccol] = h;
    if (t == 511) {
      hT[(size_t)(gb * 16 + crow) * 512 + gc * 16 + ccol] = h;
      cT[(size_t)(gb * 16 + crow) * 512 + gc * 16 + ccol] = c;
    }
  }
}

// ---------------------------------------------------------------------------
extern "C" void kernel_launch(void* const* d_in, const int* in_sizes, int n_in,
                              void* d_out, int out_size, void* d_ws, size_t ws_size,
                              hipStream_t stream)
{
  const float* x    = (const float*)d_in[0];
  const float* h0   = (const float*)d_in[1];
  const float* c0   = (const float*)d_in[2];
  const float* W_ii = (const float*)d_in[3];
  const float* b_ii = (const float*)d_in[4];
  const float* W_if = (const float*)d_in[5];
  const float* b_if = (const float*)d_in[6];
  const float* W_ig = (const float*)d_in[7];
  const float* b_ig = (const float*)d_in[8];
  const float* W_io = (const float*)d_in[9];
  const float* b_io = (const float*)d_in[10];
  const float* W_hi = (const float*)d_in[11];
  const float* b_hi = (const float*)d_in[12];
  const float* W_hf = (const float*)d_in[13];
  const float* b_hf = (const float*)d_in[14];
  const float* W_hg = (const float*)d_in[15];
  const float* b_hg = (const float*)d_in[16];
  const float* W_ho = (const float*)d_in[17];
  const float* b_ho = (const float*)d_in[18];
  unsigned char* ws = (unsigned char*)d_ws;
  float* out = (float*)d_out;

  hipLaunchKernelGGL(lstm_prep, dim3(1024), dim3(256), 0, stream,
                     W_ii, W_if, W_ig, W_io, b_ii, b_if, b_ig, b_io,
                     b_hi, b_hf, b_hg, b_ho, h0, ws);
  hipLaunchKernelGGL(lstm_fused, dim3(256), dim3(256), 0, stream,
                     x, W_hi, W_hf, W_hg, W_ho, c0, ws, out);
}

// Round 12
// 1078.797 us; speedup vs baseline: 1.0867x; 1.0867x over previous
//
#include <hip/hip_runtime.h>
#include <stdint.h>

// ---------------------------------------------------------------------------
// LSTM  T=512, B=64, I=H=512.
// r12 = r9 byte-exact (best measured: total 1102us, rec 948us) + ONE guarded
//       trim in the bandwidth-bound phase: prep pre-converts x -> bf16 (xb),
//       GEMM A-staging reads bf16 (halves L3 re-read volume, removes cvt).
//       ws-guarded: if ws_size < XB_OFF+33.5MB, falls back to exact r9 path.
//       r11 lesson: never co-locate BW work with the latency-critical chain.
// ---------------------------------------------------------------------------

typedef __attribute__((ext_vector_type(8))) short    short8;   // 8 x bf16
typedef __attribute__((ext_vector_type(4))) float    f32x4;
typedef __attribute__((ext_vector_type(4))) unsigned u32x4;
typedef __attribute__((ext_vector_type(2))) unsigned u32x2;

// ws layout (bytes)
#define XG_OFF    0ull                  // 134,217,728  (32768x2048 bf16, micro-tiled)
#define WBT_OFF   134217728ull          //   2,097,152  (2048 cols x 512 k bf16)
#define BIAS_OFF  136314880ull          //       8,192  (2048 f32)
#define HW_OFF    136323072ull          //     262,144  (2 par x 4 gb x 4 ws x 16 row x 64 u64)
#define XB_OFF    136585216ull          //  33,554,432  (x as bf16, optional)
#define WS_XB_NEED (XB_OFF + 33554432ull)

static __device__ __forceinline__ unsigned short f2bf(float f) {
  unsigned u = __float_as_uint(f);
  unsigned r = (u + 0x7FFFu + ((u >> 16) & 1u)) >> 16;   // RNE to bf16
  return (unsigned short)r;
}
static __device__ __forceinline__ float bf2f(unsigned short u) {
  return __uint_as_float(((unsigned)u) << 16);
}
static __device__ __forceinline__ float sigmoidf_(float x) {
  return 1.0f / (1.0f + __expf(-x));
}
static __device__ __forceinline__ float tanhf_(float x) {
  return 1.0f - 2.0f / (__expf(2.0f * x) + 1.0f);
}

// ---------------------------------------------------------------------------
__global__ void lstm_prep(const float* __restrict__ W_ii, const float* __restrict__ W_if,
                          const float* __restrict__ W_ig, const float* __restrict__ W_io,
                          const float* __restrict__ b_ii, const float* __restrict__ b_if,
                          const float* __restrict__ b_ig, const float* __restrict__ b_io,
                          const float* __restrict__ b_hi, const float* __restrict__ b_hf,
                          const float* __restrict__ b_hg, const float* __restrict__ b_ho,
                          const float* __restrict__ h0, const float* __restrict__ x,
                          unsigned char* ws, int have_xb)
{
  unsigned short*     WbT  = (unsigned short*)(ws + WBT_OFF);
  float*              bias = (float*)(ws + BIAS_OFF);
  unsigned long long* hw64 = (unsigned long long*)(ws + HW_OFF);

  const int gid = blockIdx.x * blockDim.x + threadIdx.x;
  const int gsz = gridDim.x * blockDim.x;

  // WbT[gcol][k] = bf16(Wx[k][col]); gcol = g*512 + c  (write-coalesced in k)
  for (int i = gid; i < 4 * 512 * 512; i += gsz) {
    int g = i >> 18, rem = i & 262143, c = rem >> 9, k = rem & 511;
    const float* W = (g == 0) ? W_ii : (g == 1) ? W_if : (g == 2) ? W_ig : W_io;
    WbT[(size_t)(g * 512 + c) * 512 + k] = f2bf(W[(size_t)k * 512 + c]);
  }
  // combined bias
  for (int i = gid; i < 2048; i += gsz) {
    int g = i >> 9, c = i & 511;
    const float* bi = (g == 0) ? b_ii : (g == 1) ? b_if : (g == 2) ? b_ig : b_io;
    const float* bh = (g == 0) ? b_hi : (g == 1) ? b_hf : (g == 2) ? b_hg : b_ho;
    bias[i] = bi[c] + bh[c];
  }
  // parity 0: h0 packed, tag 0.  Channel idx = (((par*4+gb)*4+ws)*16+row)*64+c
  for (int i = gid; i < 64 * 256; i += gsz) {
    int r = i >> 8, wc = i & 255;
    int gb = r >> 4, row = r & 15, wsl = wc >> 6, c = wc & 63;
    unsigned lo = f2bf(h0[(size_t)r * 512 + wc * 2]);
    unsigned hi = f2bf(h0[(size_t)r * 512 + wc * 2 + 1]);
    hw64[((size_t)(gb * 4 + wsl) * 16 + row) * 64 + c] =
        (unsigned long long)(lo | (hi << 16));   // hi32 tag == 0
  }
  // parity 1: invalid tag (also clears stale tags from a previous replay)
  for (int i = gid; i < 64 * 256; i += gsz)
    hw64[16384 + i] = 0xFFFFFFFF00000000ull;

  // optional: x -> bf16 staging (coalesced, 8 elems/iter); bit-identical to
  // the per-tile f2bf the GEMM otherwise applies.
  if (have_xb) {
    unsigned short* xb = (unsigned short*)(ws + XB_OFF);
    for (int i = gid; i < 2097152; i += gsz) {
      const float4 v0 = *reinterpret_cast<const float4*>(&x[(size_t)i * 8]);
      const float4 v1 = *reinterpret_cast<const float4*>(&x[(size_t)i * 8 + 4]);
      u32x4 p;
      p[0] = (unsigned)f2bf(v0.x) | ((unsigned)f2bf(v0.y) << 16);
      p[1] = (unsigned)f2bf(v0.z) | ((unsigned)f2bf(v0.w) << 16);
      p[2] = (unsigned)f2bf(v1.x) | ((unsigned)f2bf(v1.y) << 16);
      p[3] = (unsigned)f2bf(v1.z) | ((unsigned)f2bf(v1.w) << 16);
      *reinterpret_cast<u32x4*>(&xb[(size_t)i * 8]) = p;
    }
  }
}

// ---------------------------------------------------------------------------
// Phase 1: xg = x @ Wx + b.  128x128 tile, BK=64, 4 waves (2x2 of 64x64).
// xg layout: [rowtile(2048)][coltile(128)][256 elems], elem e within 16x16
// micro-tile: e = (row&15)>>2 *64 + (col&15)*4 + (row&3)   (matches MFMA C/D)
__global__ __launch_bounds__(256) void xproj_gemm(const float* __restrict__ x,
                                                  unsigned char* ws, int have_xb)
{
  const unsigned short* WbT  = (const unsigned short*)(ws + WBT_OFF);
  const float*          bias = (const float*)(ws + BIAS_OFF);
  unsigned short*       xg   = (unsigned short*)(ws + XG_OFF);
  const unsigned short* xb   = (const unsigned short*)(ws + XB_OFF);

  __shared__ unsigned short As[128 * 64];   // [row][k] bf16
  __shared__ unsigned short Bs[128 * 64];   // [col][k] bf16

  // XCD-aware swizzle (4096 % 8 == 0 -> bijective)
  const int bid  = (int)blockIdx.x;
  const int bidx = (bid & 7) * 512 + (bid >> 3);
  const int bm = bidx >> 4, bn = bidx & 15;
  const int row0 = bm * 128, col0 = bn * 128;

  const int tid = threadIdx.x, lane = tid & 63, w = tid >> 6;
  const int wr = w >> 1, wc = w & 1;

  f32x4 acc[4][4] = {};

  for (int k0 = 0; k0 < 512; k0 += 64) {
    __syncthreads();
    // stage A: bf16 direct copy (have_xb) or fp32 -> bf16 (fallback)
    if (have_xb) {
#pragma unroll
      for (int u = 0; u < 4; ++u) {
        int idx = u * 256 + tid;          // 0..1023
        int cl = idx >> 3, ch = idx & 7;  // 8 bf16 each
        *reinterpret_cast<uint4*>(&As[cl * 64 + ch * 8]) =
            *reinterpret_cast<const uint4*>(&xb[(size_t)(row0 + cl) * 512 + k0 + ch * 8]);
      }
    } else {
#pragma unroll
      for (int u = 0; u < 8; ++u) {
        int idx = u * 256 + tid;            // 0..2047
        int r = idx >> 4, quad = idx & 15;  // 4 floats each
        const float4 v = *reinterpret_cast<const float4*>(
            &x[(size_t)(row0 + r) * 512 + k0 + quad * 4]);
        uint2 p;
        p.x = (unsigned)f2bf(v.x) | ((unsigned)f2bf(v.y) << 16);
        p.y = (unsigned)f2bf(v.z) | ((unsigned)f2bf(v.w) << 16);
        *reinterpret_cast<uint2*>(&As[r * 64 + quad * 4]) = p;
      }
    }
    // stage B: already bf16 in WbT
#pragma unroll
    for (int u = 0; u < 4; ++u) {
      int idx = u * 256 + tid;            // 0..1023
      int cl = idx >> 3, ch = idx & 7;    // 8 bf16 each
      *reinterpret_cast<uint4*>(&Bs[cl * 64 + ch * 8]) =
          *reinterpret_cast<const uint4*>(&WbT[(size_t)(col0 + cl) * 512 + k0 + ch * 8]);
    }
    __syncthreads();
#pragma unroll
    for (int kk = 0; kk < 64; kk += 32) {
      short8 a[4], b[4];
#pragma unroll
      for (int m = 0; m < 4; ++m)
        a[m] = *reinterpret_cast<const short8*>(
            &As[(wr * 64 + m * 16 + (lane & 15)) * 64 + kk + (lane >> 4) * 8]);
#pragma unroll
      for (int n = 0; n < 4; ++n)
        b[n] = *reinterpret_cast<const short8*>(
            &Bs[(wc * 64 + n * 16 + (lane & 15)) * 64 + kk + (lane >> 4) * 8]);
#pragma unroll
      for (int m = 0; m < 4; ++m)
#pragma unroll
        for (int n = 0; n < 4; ++n)
          acc[m][n] = __builtin_amdgcn_mfma_f32_16x16x32_bf16(a[m], b[n], acc[m][n], 0, 0, 0);
    }
  }
  // epilogue: +bias, bf16, micro-tiled fully-coalesced store (uint2 per lane)
#pragma unroll
  for (int m = 0; m < 4; ++m) {
    int rowtile = bm * 8 + wr * 4 + m;
#pragma unroll
    for (int n = 0; n < 4; ++n) {
      int coltile = bn * 8 + wc * 4 + n;
      float bv = bias[coltile * 16 + (lane & 15)];
      uint2 p;
      p.x = (unsigned)f2bf(acc[m][n][0] + bv) | ((unsigned)f2bf(acc[m][n][1] + bv) << 16);
      p.y = (unsigned)f2bf(acc[m][n][2] + bv) | ((unsigned)f2bf(acc[m][n][3] + bv) << 16);
      *reinterpret_cast<uint2*>(&xg[((size_t)rowtile * 128 + coltile) * 256 + lane * 4]) = p;
    }
  }
}

// ---------------------------------------------------------------------------
// Phase 2: persistent recurrence. 128 wgs = 4 batch-groups x 32 col-groups.
// wave w handles K-slice [w*128, w*128+128) for ALL 4 gates of its 16 h-cols.
// Channel block [par][gb][w] = 16 rows x 64 u64 words = 8KB, contiguous.
// FUSED BULK-POLL: the coalesced 8 x global_load_dwordx4 (sc0 sc1) IS the
// poll; in-register tag verify; s_sleep(1) backoff per miss. On success the
// h data is already in registers. Bounded by a global budget (anti-hang).
__global__ __launch_bounds__(256, 1) void lstm_rec(
    const float* __restrict__ Whi, const float* __restrict__ Whf,
    const float* __restrict__ Whg, const float* __restrict__ Who,
    const float* __restrict__ c0, unsigned char* ws, float* __restrict__ out)
{
  const int gb = (int)blockIdx.x & 3;        // batch group (16 rows)
  const int gc = (int)blockIdx.x >> 2;       // col group (16 h-cols)
  const int tid = threadIdx.x, lane = tid & 63, w = tid >> 6;

  const unsigned short* xg = (const unsigned short*)(ws + XG_OFF);
  unsigned long long*   hw64 = (unsigned long long*)(ws + HW_OFF);

  __shared__ unsigned hdat[4][1024];         // per-wave data u32, bank-swizzled
  __shared__ float glds[2][4][4][16][16];    // [par][wave][gate][row][col]

  // ---- load Wh fragments (split bf16 hi+lo), K-slice of this wave ----
  short8 bhi[4][4], blo[4][4];               // [gate][kkl]
  {
    const int colg = gc * 16 + (lane & 15);
    const int krow = (lane >> 4) * 8;
#pragma unroll
    for (int g = 0; g < 4; ++g) {
      const float* P = (g == 0) ? Whi : (g == 1) ? Whf : (g == 2) ? Whg : Who;
#pragma unroll
      for (int kkl = 0; kkl < 4; ++kkl) {
        short8 h8, l8;
#pragma unroll
        for (int i = 0; i < 8; ++i) {
          int k = w * 128 + kkl * 32 + krow + i;
          float wv = P[(size_t)k * 512 + colg];
          unsigned short hb = f2bf(wv);
          h8[i] = (short)hb;
          l8[i] = (short)f2bf(wv - bf2f(hb));
        }
        bhi[g][kkl] = h8; blo[g][kkl] = l8;
      }
    }
  }

  const int crow = tid >> 4, ccol = tid & 15;       // this thread's (row,col)
  float c = c0[(size_t)(gb * 16 + crow) * 512 + gc * 16 + ccol];

  float* hT = out + 16777216;
  float* cT = out + 16777216 + 32768;
  const int e_ix = (crow >> 2) * 64 + ccol * 4 + (crow & 3);   // micro-tile elem
  int bleft = 30000000;                      // global poll budget (anti-hang)

  for (int t = 0; t < 512; ++t) {
    // xg prefetch (independent of recurrence; issued before the poll)
    const size_t xb = (size_t)(t * 4 + gb) * 128 * 256;
    float xgi = bf2f(xg[xb + (size_t)(0 * 32 + gc) * 256 + e_ix]);
    float xgf = bf2f(xg[xb + (size_t)(1 * 32 + gc) * 256 + e_ix]);
    float xgg = bf2f(xg[xb + (size_t)(2 * 32 + gc) * 256 + e_ix]);
    float xgo = bf2f(xg[xb + (size_t)(3 * 32 + gc) * 256 + e_ix]);

    const int par = t & 1;
    const unsigned long long* blk =
        hw64 + (size_t)((par * 4 + gb) * 4 + w) * 1024;
    const unsigned tagw = (unsigned)t;

    // ---- fused bulk-poll: the coalesced read IS the poll ----
    u32x4 dv[8];
    const char* lbase = (const char*)blk + lane * 16;
    for (;;) {
#pragma unroll
      for (int i = 0; i < 8; ++i)
        asm volatile("global_load_dwordx4 %0, %1, off sc0 sc1"
                     : "=v"(dv[i]) : "v"(lbase + (size_t)i * 1024));
      asm volatile("s_waitcnt vmcnt(0)"
                   : "+v"(dv[0]), "+v"(dv[1]), "+v"(dv[2]), "+v"(dv[3]),
                     "+v"(dv[4]), "+v"(dv[5]), "+v"(dv[6]), "+v"(dv[7])
                   :: "memory");
      bool ok = true;
#pragma unroll
      for (int i = 0; i < 8; ++i)
        ok = ok && (dv[i][1] == tagw) && (dv[i][3] == tagw);
      if (__all(ok) || --bleft <= 0) break;
      __builtin_amdgcn_s_sleep(1);           // backoff: cap poll congestion
    }

    // ---- redistribute data u32s via swizzled LDS (conflict-free-ish)
#pragma unroll
    for (int i = 0; i < 8; ++i) {
      int k = i * 128 + lane * 2;
      int row = k >> 6;
      int sw = k ^ ((row & 7) << 2);
      u32x2 p2; p2[0] = dv[i][0]; p2[1] = dv[i][2];
      *reinterpret_cast<u32x2*>(&hdat[w][sw]) = p2;
    }
    asm volatile("s_waitcnt lgkmcnt(0)" ::: "memory");
    __builtin_amdgcn_sched_barrier(0);

    // ---- MFMA partials over this wave's K-slice
    f32x4 acc[4] = {};
#pragma unroll
    for (int kkl = 0; kkl < 4; ++kkl) {
      int base = (lane & 15) * 64 + kkl * 16 + (lane >> 4) * 4;
      int sw = base ^ ((lane & 7) << 2);
      union { u32x4 v; short8 s; } fr;
      fr.v = *reinterpret_cast<const u32x4*>(&hdat[w][sw]);
#pragma unroll
      for (int g = 0; g < 4; ++g) {
        acc[g] = __builtin_amdgcn_mfma_f32_16x16x32_bf16(fr.s, bhi[g][kkl], acc[g], 0, 0, 0);
        acc[g] = __builtin_amdgcn_mfma_f32_16x16x32_bf16(fr.s, blo[g][kkl], acc[g], 0, 0, 0);
      }
    }
    // ---- exchange K-partials via LDS (parity buffer, single barrier)
#pragma unroll
    for (int g = 0; g < 4; ++g)
#pragma unroll
      for (int j = 0; j < 4; ++j)
        glds[par][w][g][(lane >> 4) * 4 + j][lane & 15] = acc[g][j];
    __syncthreads();

    float gi = xgi, gf = xgf, gg = xgg, go = xgo;
#pragma unroll
    for (int ww = 0; ww < 4; ++ww) {
      gi += glds[par][ww][0][crow][ccol];
      gf += glds[par][ww][1][crow][ccol];
      gg += glds[par][ww][2][crow][ccol];
      go += glds[par][ww][3][crow][ccol];
    }
    float iv = sigmoidf_(gi), fv = sigmoidf_(gf), gv = tanhf_(gg), ov = sigmoidf_(go);
    c = fv * c + iv * gv;
    float h = ov * c;                       // NOTE: no tanh(c), per reference

    // ---- publish h_{t+1} (tag rides in the same 8B word; coalesced lines)
    if (t != 511) {
      float hp = __shfl_xor(h, 1);
      if ((ccol & 1) == 0) {
        unsigned data = (unsigned)f2bf(h) | ((unsigned)f2bf(hp) << 16);
        u32x2 wp; wp[0] = data; wp[1] = (unsigned)(t + 1);
        unsigned long long* dst =
            hw64 + ((size_t)((((t + 1) & 1) * 4 + gb) * 4 + (gc >> 3)) * 16 + crow) * 64 +
            (gc & 7) * 8 + (ccol >> 1);
        asm volatile("global_store_dwordx2 %0, %1, off sc0 sc1"
                     :: "v"(dst), "v"(wp) : "memory");
      }
    }

    out[(size_t)t * 32768 + (size_t)(gb * 16 + crow) * 512 + gc * 16 + ccol] = h;
    if (t == 511) {
      hT[(size_t)(gb * 16 + crow) * 512 + gc * 16 + ccol] = h;
      cT[(size_t)(gb * 16 + crow) * 512 + gc * 16 + ccol] = c;
    }
  }
}

// ---------------------------------------------------------------------------
extern "C" void kernel_launch(void* const* d_in, const int* in_sizes, int n_in,
                              void* d_out, int out_size, void* d_ws, size_t ws_size,
                              hipStream_t stream)
{
  const float* x    = (const float*)d_in[0];
  const float* h0   = (const float*)d_in[1];
  const float* c0   = (const float*)d_in[2];
  const float* W_ii = (const float*)d_in[3];
  const float* b_ii = (const float*)d_in[4];
  const float* W_if = (const float*)d_in[5];
  const float* b_if = (const float*)d_in[6];
  const float* W_ig = (const float*)d_in[7];
  const float* b_ig = (const float*)d_in[8];
  const float* W_io = (const float*)d_in[9];
  const float* b_io = (const float*)d_in[10];
  const float* W_hi = (const float*)d_in[11];
  const float* b_hi = (const float*)d_in[12];
  const float* W_hf = (const float*)d_in[13];
  const float* b_hf = (const float*)d_in[14];
  const float* W_hg = (const float*)d_in[15];
  const float* b_hg = (const float*)d_in[16];
  const float* W_ho = (const float*)d_in[17];
  const float* b_ho = (const float*)d_in[18];
  unsigned char* ws = (unsigned char*)d_ws;
  float* out = (float*)d_out;

  const int have_xb = (ws_size >= (size_t)WS_XB_NEED) ? 1 : 0;

  hipLaunchKernelGGL(lstm_prep, dim3(1024), dim3(256), 0, stream,
                     W_ii, W_if, W_ig, W_io, b_ii, b_if, b_ig, b_io,
                     b_hi, b_hf, b_hg, b_ho, h0, x, ws, have_xb);
  hipLaunchKernelGGL(xproj_gemm, dim3(4096), dim3(256), 0, stream, x, ws, have_xb);
  hipLaunchKernelGGL(lstm_rec, dim3(128), dim3(256), 0, stream,
                     W_hi, W_hf, W_hg, W_ho, c0, ws, out);
}

// Round 13
// 1052.115 us; speedup vs baseline: 1.1143x; 1.0254x over previous
//
#include <hip/hip_runtime.h>
#include <stdint.h>

// ---------------------------------------------------------------------------
// LSTM  T=512, B=64, I=H=512.
// r13 = r12 (best: total 1079us, rec 943us) + ONE change in rec: Wh held as
//       plain bf16 (lo-split dropped) -> 16 MFMAs/wave/step instead of 32.
//       Error model: extra gate error ~0.002 (same order as existing bf16
//       h/xg rounding); predicted absmax 0.005-0.010 vs threshold 0.0209.
// ---------------------------------------------------------------------------

typedef __attribute__((ext_vector_type(8))) short    short8;   // 8 x bf16
typedef __attribute__((ext_vector_type(4))) float    f32x4;
typedef __attribute__((ext_vector_type(4))) unsigned u32x4;
typedef __attribute__((ext_vector_type(2))) unsigned u32x2;

// ws layout (bytes)
#define XG_OFF    0ull                  // 134,217,728  (32768x2048 bf16, micro-tiled)
#define WBT_OFF   134217728ull          //   2,097,152  (2048 cols x 512 k bf16)
#define BIAS_OFF  136314880ull          //       8,192  (2048 f32)
#define HW_OFF    136323072ull          //     262,144  (2 par x 4 gb x 4 ws x 16 row x 64 u64)
#define XB_OFF    136585216ull          //  33,554,432  (x as bf16, optional)
#define WS_XB_NEED (XB_OFF + 33554432ull)

static __device__ __forceinline__ unsigned short f2bf(float f) {
  unsigned u = __float_as_uint(f);
  unsigned r = (u + 0x7FFFu + ((u >> 16) & 1u)) >> 16;   // RNE to bf16
  return (unsigned short)r;
}
static __device__ __forceinline__ float bf2f(unsigned short u) {
  return __uint_as_float(((unsigned)u) << 16);
}
static __device__ __forceinline__ float sigmoidf_(float x) {
  return 1.0f / (1.0f + __expf(-x));
}
static __device__ __forceinline__ float tanhf_(float x) {
  return 1.0f - 2.0f / (__expf(2.0f * x) + 1.0f);
}

// ---------------------------------------------------------------------------
__global__ void lstm_prep(const float* __restrict__ W_ii, const float* __restrict__ W_if,
                          const float* __restrict__ W_ig, const float* __restrict__ W_io,
                          const float* __restrict__ b_ii, const float* __restrict__ b_if,
                          const float* __restrict__ b_ig, const float* __restrict__ b_io,
                          const float* __restrict__ b_hi, const float* __restrict__ b_hf,
                          const float* __restrict__ b_hg, const float* __restrict__ b_ho,
                          const float* __restrict__ h0, const float* __restrict__ x,
                          unsigned char* ws, int have_xb)
{
  unsigned short*     WbT  = (unsigned short*)(ws + WBT_OFF);
  float*              bias = (float*)(ws + BIAS_OFF);
  unsigned long long* hw64 = (unsigned long long*)(ws + HW_OFF);

  const int gid = blockIdx.x * blockDim.x + threadIdx.x;
  const int gsz = gridDim.x * blockDim.x;

  // WbT[gcol][k] = bf16(Wx[k][col]); gcol = g*512 + c  (write-coalesced in k)
  for (int i = gid; i < 4 * 512 * 512; i += gsz) {
    int g = i >> 18, rem = i & 262143, c = rem >> 9, k = rem & 511;
    const float* W = (g == 0) ? W_ii : (g == 1) ? W_if : (g == 2) ? W_ig : W_io;
    WbT[(size_t)(g * 512 + c) * 512 + k] = f2bf(W[(size_t)k * 512 + c]);
  }
  // combined bias
  for (int i = gid; i < 2048; i += gsz) {
    int g = i >> 9, c = i & 511;
    const float* bi = (g == 0) ? b_ii : (g == 1) ? b_if : (g == 2) ? b_ig : b_io;
    const float* bh = (g == 0) ? b_hi : (g == 1) ? b_hf : (g == 2) ? b_hg : b_ho;
    bias[i] = bi[c] + bh[c];
  }
  // parity 0: h0 packed, tag 0.  Channel idx = (((par*4+gb)*4+ws)*16+row)*64+c
  for (int i = gid; i < 64 * 256; i += gsz) {
    int r = i >> 8, wc = i & 255;
    int gb = r >> 4, row = r & 15, wsl = wc >> 6, c = wc & 63;
    unsigned lo = f2bf(h0[(size_t)r * 512 + wc * 2]);
    unsigned hi = f2bf(h0[(size_t)r * 512 + wc * 2 + 1]);
    hw64[((size_t)(gb * 4 + wsl) * 16 + row) * 64 + c] =
        (unsigned long long)(lo | (hi << 16));   // hi32 tag == 0
  }
  // parity 1: invalid tag (also clears stale tags from a previous replay)
  for (int i = gid; i < 64 * 256; i += gsz)
    hw64[16384 + i] = 0xFFFFFFFF00000000ull;

  // optional: x -> bf16 staging (coalesced, 8 elems/iter); bit-identical to
  // the per-tile f2bf the GEMM otherwise applies.
  if (have_xb) {
    unsigned short* xb = (unsigned short*)(ws + XB_OFF);
    for (int i = gid; i < 2097152; i += gsz) {
      const float4 v0 = *reinterpret_cast<const float4*>(&x[(size_t)i * 8]);
      const float4 v1 = *reinterpret_cast<const float4*>(&x[(size_t)i * 8 + 4]);
      u32x4 p;
      p[0] = (unsigned)f2bf(v0.x) | ((unsigned)f2bf(v0.y) << 16);
      p[1] = (unsigned)f2bf(v0.z) | ((unsigned)f2bf(v0.w) << 16);
      p[2] = (unsigned)f2bf(v1.x) | ((unsigned)f2bf(v1.y) << 16);
      p[3] = (unsigned)f2bf(v1.z) | ((unsigned)f2bf(v1.w) << 16);
      *reinterpret_cast<u32x4*>(&xb[(size_t)i * 8]) = p;
    }
  }
}

// ---------------------------------------------------------------------------
// Phase 1: xg = x @ Wx + b.  128x128 tile, BK=64, 4 waves (2x2 of 64x64).
// xg layout: [rowtile(2048)][coltile(128)][256 elems], elem e within 16x16
// micro-tile: e = (row&15)>>2 *64 + (col&15)*4 + (row&3)   (matches MFMA C/D)
__global__ __launch_bounds__(256) void xproj_gemm(const float* __restrict__ x,
                                                  unsigned char* ws, int have_xb)
{
  const unsigned short* WbT  = (const unsigned short*)(ws + WBT_OFF);
  const float*          bias = (const float*)(ws + BIAS_OFF);
  unsigned short*       xg   = (unsigned short*)(ws + XG_OFF);
  const unsigned short* xb   = (const unsigned short*)(ws + XB_OFF);

  __shared__ unsigned short As[128 * 64];   // [row][k] bf16
  __shared__ unsigned short Bs[128 * 64];   // [col][k] bf16

  // XCD-aware swizzle (4096 % 8 == 0 -> bijective)
  const int bid  = (int)blockIdx.x;
  const int bidx = (bid & 7) * 512 + (bid >> 3);
  const int bm = bidx >> 4, bn = bidx & 15;
  const int row0 = bm * 128, col0 = bn * 128;

  const int tid = threadIdx.x, lane = tid & 63, w = tid >> 6;
  const int wr = w >> 1, wc = w & 1;

  f32x4 acc[4][4] = {};

  for (int k0 = 0; k0 < 512; k0 += 64) {
    __syncthreads();
    // stage A: bf16 direct copy (have_xb) or fp32 -> bf16 (fallback)
    if (have_xb) {
#pragma unroll
      for (int u = 0; u < 4; ++u) {
        int idx = u * 256 + tid;          // 0..1023
        int cl = idx >> 3, ch = idx & 7;  // 8 bf16 each
        *reinterpret_cast<uint4*>(&As[cl * 64 + ch * 8]) =
            *reinterpret_cast<const uint4*>(&xb[(size_t)(row0 + cl) * 512 + k0 + ch * 8]);
      }
    } else {
#pragma unroll
      for (int u = 0; u < 8; ++u) {
        int idx = u * 256 + tid;            // 0..2047
        int r = idx >> 4, quad = idx & 15;  // 4 floats each
        const float4 v = *reinterpret_cast<const float4*>(
            &x[(size_t)(row0 + r) * 512 + k0 + quad * 4]);
        uint2 p;
        p.x = (unsigned)f2bf(v.x) | ((unsigned)f2bf(v.y) << 16);
        p.y = (unsigned)f2bf(v.z) | ((unsigned)f2bf(v.w) << 16);
        *reinterpret_cast<uint2*>(&As[r * 64 + quad * 4]) = p;
      }
    }
    // stage B: already bf16 in WbT
#pragma unroll
    for (int u = 0; u < 4; ++u) {
      int idx = u * 256 + tid;            // 0..1023
      int cl = idx >> 3, ch = idx & 7;    // 8 bf16 each
      *reinterpret_cast<uint4*>(&Bs[cl * 64 + ch * 8]) =
          *reinterpret_cast<const uint4*>(&WbT[(size_t)(col0 + cl) * 512 + k0 + ch * 8]);
    }
    __syncthreads();
#pragma unroll
    for (int kk = 0; kk < 64; kk += 32) {
      short8 a[4], b[4];
#pragma unroll
      for (int m = 0; m < 4; ++m)
        a[m] = *reinterpret_cast<const short8*>(
            &As[(wr * 64 + m * 16 + (lane & 15)) * 64 + kk + (lane >> 4) * 8]);
#pragma unroll
      for (int n = 0; n < 4; ++n)
        b[n] = *reinterpret_cast<const short8*>(
            &Bs[(wc * 64 + n * 16 + (lane & 15)) * 64 + kk + (lane >> 4) * 8]);
#pragma unroll
      for (int m = 0; m < 4; ++m)
#pragma unroll
        for (int n = 0; n < 4; ++n)
          acc[m][n] = __builtin_amdgcn_mfma_f32_16x16x32_bf16(a[m], b[n], acc[m][n], 0, 0, 0);
    }
  }
  // epilogue: +bias, bf16, micro-tiled fully-coalesced store (uint2 per lane)
#pragma unroll
  for (int m = 0; m < 4; ++m) {
    int rowtile = bm * 8 + wr * 4 + m;
#pragma unroll
    for (int n = 0; n < 4; ++n) {
      int coltile = bn * 8 + wc * 4 + n;
      float bv = bias[coltile * 16 + (lane & 15)];
      uint2 p;
      p.x = (unsigned)f2bf(acc[m][n][0] + bv) | ((unsigned)f2bf(acc[m][n][1] + bv) << 16);
      p.y = (unsigned)f2bf(acc[m][n][2] + bv) | ((unsigned)f2bf(acc[m][n][3] + bv) << 16);
      *reinterpret_cast<uint2*>(&xg[((size_t)rowtile * 128 + coltile) * 256 + lane * 4]) = p;
    }
  }
}

// ---------------------------------------------------------------------------
// Phase 2: persistent recurrence. 128 wgs = 4 batch-groups x 32 col-groups.
// wave w handles K-slice [w*128, w*128+128) for ALL 4 gates of its 16 h-cols.
// Channel block [par][gb][w] = 16 rows x 64 u64 words = 8KB, contiguous.
// FUSED BULK-POLL: the coalesced 8 x global_load_dwordx4 (sc0 sc1) IS the
// poll; in-register tag verify; s_sleep(1) backoff per miss. Wh plain bf16
// (4 MFMAs per kkl). Bounded by a global budget (anti-hang).
__global__ __launch_bounds__(256, 1) void lstm_rec(
    const float* __restrict__ Whi, const float* __restrict__ Whf,
    const float* __restrict__ Whg, const float* __restrict__ Who,
    const float* __restrict__ c0, unsigned char* ws, float* __restrict__ out)
{
  const int gb = (int)blockIdx.x & 3;        // batch group (16 rows)
  const int gc = (int)blockIdx.x >> 2;       // col group (16 h-cols)
  const int tid = threadIdx.x, lane = tid & 63, w = tid >> 6;

  const unsigned short* xg = (const unsigned short*)(ws + XG_OFF);
  unsigned long long*   hw64 = (unsigned long long*)(ws + HW_OFF);

  __shared__ unsigned hdat[4][1024];         // per-wave data u32, bank-swizzled
  __shared__ float glds[2][4][4][16][16];    // [par][wave][gate][row][col]

  // ---- load Wh fragments (plain bf16), K-slice of this wave ----
  short8 bhi[4][4];                          // [gate][kkl]
  {
    const int colg = gc * 16 + (lane & 15);
    const int krow = (lane >> 4) * 8;
#pragma unroll
    for (int g = 0; g < 4; ++g) {
      const float* P = (g == 0) ? Whi : (g == 1) ? Whf : (g == 2) ? Whg : Who;
#pragma unroll
      for (int kkl = 0; kkl < 4; ++kkl) {
        short8 h8;
#pragma unroll
        for (int i = 0; i < 8; ++i) {
          int k = w * 128 + kkl * 32 + krow + i;
          h8[i] = (short)f2bf(P[(size_t)k * 512 + colg]);
        }
        bhi[g][kkl] = h8;
      }
    }
  }

  const int crow = tid >> 4, ccol = tid & 15;       // this thread's (row,col)
  float c = c0[(size_t)(gb * 16 + crow) * 512 + gc * 16 + ccol];

  float* hT = out + 16777216;
  float* cT = out + 16777216 + 32768;
  const int e_ix = (crow >> 2) * 64 + ccol * 4 + (crow & 3);   // micro-tile elem
  int bleft = 30000000;                      // global poll budget (anti-hang)

  for (int t = 0; t < 512; ++t) {
    // xg prefetch (independent of recurrence; issued before the poll)
    const size_t xb = (size_t)(t * 4 + gb) * 128 * 256;
    float xgi = bf2f(xg[xb + (size_t)(0 * 32 + gc) * 256 + e_ix]);
    float xgf = bf2f(xg[xb + (size_t)(1 * 32 + gc) * 256 + e_ix]);
    float xgg = bf2f(xg[xb + (size_t)(2 * 32 + gc) * 256 + e_ix]);
    float xgo = bf2f(xg[xb + (size_t)(3 * 32 + gc) * 256 + e_ix]);

    const int par = t & 1;
    const unsigned long long* blk =
        hw64 + (size_t)((par * 4 + gb) * 4 + w) * 1024;
    const unsigned tagw = (unsigned)t;

    // ---- fused bulk-poll: the coalesced read IS the poll ----
    u32x4 dv[8];
    const char* lbase = (const char*)blk + lane * 16;
    for (;;) {
#pragma unroll
      for (int i = 0; i < 8; ++i)
        asm volatile("global_load_dwordx4 %0, %1, off sc0 sc1"
                     : "=v"(dv[i]) : "v"(lbase + (size_t)i * 1024));
      asm volatile("s_waitcnt vmcnt(0)"
                   : "+v"(dv[0]), "+v"(dv[1]), "+v"(dv[2]), "+v"(dv[3]),
                     "+v"(dv[4]), "+v"(dv[5]), "+v"(dv[6]), "+v"(dv[7])
                   :: "memory");
      bool ok = true;
#pragma unroll
      for (int i = 0; i < 8; ++i)
        ok = ok && (dv[i][1] == tagw) && (dv[i][3] == tagw);
      if (__all(ok) || --bleft <= 0) break;
      __builtin_amdgcn_s_sleep(1);           // backoff: cap poll congestion
    }

    // ---- redistribute data u32s via swizzled LDS (conflict-free-ish)
#pragma unroll
    for (int i = 0; i < 8; ++i) {
      int k = i * 128 + lane * 2;
      int row = k >> 6;
      int sw = k ^ ((row & 7) << 2);
      u32x2 p2; p2[0] = dv[i][0]; p2[1] = dv[i][2];
      *reinterpret_cast<u32x2*>(&hdat[w][sw]) = p2;
    }
    asm volatile("s_waitcnt lgkmcnt(0)" ::: "memory");
    __builtin_amdgcn_sched_barrier(0);

    // ---- MFMA partials over this wave's K-slice (plain bf16 Wh)
    f32x4 acc[4] = {};
#pragma unroll
    for (int kkl = 0; kkl < 4; ++kkl) {
      int base = (lane & 15) * 64 + kkl * 16 + (lane >> 4) * 4;
      int sw = base ^ ((lane & 7) << 2);
      union { u32x4 v; short8 s; } fr;
      fr.v = *reinterpret_cast<const u32x4*>(&hdat[w][sw]);
#pragma unroll
      for (int g = 0; g < 4; ++g)
        acc[g] = __builtin_amdgcn_mfma_f32_16x16x32_bf16(fr.s, bhi[g][kkl], acc[g], 0, 0, 0);
    }
    // ---- exchange K-partials via LDS (parity buffer, single barrier)
#pragma unroll
    for (int g = 0; g < 4; ++g)
#pragma unroll
      for (int j = 0; j < 4; ++j)
        glds[par][w][g][(lane >> 4) * 4 + j][lane & 15] = acc[g][j];
    __syncthreads();

    float gi = xgi, gf = xgf, gg = xgg, go = xgo;
#pragma unroll
    for (int ww = 0; ww < 4; ++ww) {
      gi += glds[par][ww][0][crow][ccol];
      gf += glds[par][ww][1][crow][ccol];
      gg += glds[par][ww][2][crow][ccol];
      go += glds[par][ww][3][crow][ccol];
    }
    float iv = sigmoidf_(gi), fv = sigmoidf_(gf), gv = tanhf_(gg), ov = sigmoidf_(go);
    c = fv * c + iv * gv;
    float h = ov * c;                       // NOTE: no tanh(c), per reference

    // ---- publish h_{t+1} (tag rides in the same 8B word; coalesced lines)
    if (t != 511) {
      float hp = __shfl_xor(h, 1);
      if ((ccol & 1) == 0) {
        unsigned data = (unsigned)f2bf(h) | ((unsigned)f2bf(hp) << 16);
        u32x2 wp; wp[0] = data; wp[1] = (unsigned)(t + 1);
        unsigned long long* dst =
            hw64 + ((size_t)((((t + 1) & 1) * 4 + gb) * 4 + (gc >> 3)) * 16 + crow) * 64 +
            (gc & 7) * 8 + (ccol >> 1);
        asm volatile("global_store_dwordx2 %0, %1, off sc0 sc1"
                     :: "v"(dst), "v"(wp) : "memory");
      }
    }

    out[(size_t)t * 32768 + (size_t)(gb * 16 + crow) * 512 + gc * 16 + ccol] = h;
    if (t == 511) {
      hT[(size_t)(gb * 16 + crow) * 512 + gc * 16 + ccol] = h;
      cT[(size_t)(gb * 16 + crow) * 512 + gc * 16 + ccol] = c;
    }
  }
}

// ---------------------------------------------------------------------------
extern "C" void kernel_launch(void* const* d_in, const int* in_sizes, int n_in,
                              void* d_out, int out_size, void* d_ws, size_t ws_size,
                              hipStream_t stream)
{
  const float* x    = (const float*)d_in[0];
  const float* h0   = (const float*)d_in[1];
  const float* c0   = (const float*)d_in[2];
  const float* W_ii = (const float*)d_in[3];
  const float* b_ii = (const float*)d_in[4];
  const float* W_if = (const float*)d_in[5];
  const float* b_if = (const float*)d_in[6];
  const float* W_ig = (const float*)d_in[7];
  const float* b_ig = (const float*)d_in[8];
  const float* W_io = (const float*)d_in[9];
  const float* b_io = (const float*)d_in[10];
  const float* W_hi = (const float*)d_in[11];
  const float* b_hi = (const float*)d_in[12];
  const float* W_hf = (const float*)d_in[13];
  const float* b_hf = (const float*)d_in[14];
  const float* W_hg = (const float*)d_in[15];
  const float* b_hg = (const float*)d_in[16];
  const float* W_ho = (const float*)d_in[17];
  const float* b_ho = (const float*)d_in[18];
  unsigned char* ws = (unsigned char*)d_ws;
  float* out = (float*)d_out;

  const int have_xb = (ws_size >= (size_t)WS_XB_NEED) ? 1 : 0;

  hipLaunchKernelGGL(lstm_prep, dim3(1024), dim3(256), 0, stream,
                     W_ii, W_if, W_ig, W_io, b_ii, b_if, b_ig, b_io,
                     b_hi, b_hf, b_hg, b_ho, h0, x, ws, have_xb);
  hipLaunchKernelGGL(xproj_gemm, dim3(4096), dim3(256), 0, stream, x, ws, have_xb);
  hipLaunchKernelGGL(lstm_rec, dim3(128), dim3(256), 0, stream,
                     W_hi, W_hf, W_hg, W_ho, c0, ws, out);
}